// Round 4
// baseline (246.596 us; speedup 1.0000x reference)
//
#include <hip/hip_runtime.h>

// Problem constants (from reference setup_inputs):
//   fm0: [16,3,80,80,85]  -> 26,112,000 floats, 19200 rows/batch, scale 80
//   fm1: [16,3,40,40,85]  ->  6,528,000 floats,  4800 rows/batch, scale 40
//   fm2: [16,3,20,20,85]  ->  1,632,000 floats,  1200 rows/batch, scale 20
//   out: [16, 25200, 85]  -> 34,272,000 floats
//
// Round-4 configuration: the three independently-best components combined
// (never yet run together):
//   - persistent 2048-block grid-stride (steady-state waves, no churn of
//     16,735 short-lived blocks; the 6.29 TB/s copy-reference shape)
//   - nontemporal stores (round 0/3 vs round 2: ~10 us better than plain)
//   - 3-VMEM process4 (funnel-select row reconstruction, verified round 3)
// Four quarter-streams per iteration; quarters 0-2 statically level-0
// (3*Q4*4 = 25,704,000 < L0_FLOATS), so 3 of 4 streams are branch-free and
// all 8 loads of an iteration are independent/hoistable.
#define NROWS_OUT 25200
#define L0_FLOATS 26112000
#define L1_FLOATS 6528000
#define L2_FLOATS 1632000
#define TOTAL_FLOATS (L0_FLOATS + L1_FLOATS + L2_FLOATS)   // 34,272,000
#define TOTAL4   (TOTAL_FLOATS / 4)                        //  8,568,000
#define Q4       (TOTAL4 / 4)                              //  2,142,000
#define NBLOCKS  2048
#define NTHREADS (NBLOCKS * 256)                           //    524,288
#define NITER    ((Q4 + NTHREADS - 1) / NTHREADS)          //          5

typedef float v4f __attribute__((ext_vector_type(4)));

__device__ __forceinline__ float fast_sigmoid(float x) {
    // v_exp_f32 (+1 mul) + v_rcp_f32: ~4 VALU ops, rel err ~1e-6.
    float e = __expf(-x);
    return __builtin_amdgcn_rcpf(1.0f + e);
}

// One aligned float4 of a level's flat buffer. ROWS/OFF/SCALE compile-time.
//
// Alignment: f_local % 4 == 0; output shift per (b,level) is a multiple of
// 4 floats for all levels, so load and store are 16B-aligned.
//
// Row-float reconstruction (1 vec load instead of 4 scalar loads):
//   needed row floats beyond our own x are all inside ONE aligned neighbor
//   float4: prev (f-4) for c0 in 1..3, next (f+4) for c0 in 82..84, none
//   otherwise (neighbor load degenerates to own address -> L1 hit).
//   In-bounds: c0 in 1..3 => f>=4; c0>=82 => next row exists in full (last
//   float4 of a level has c0 = (ROWS85-4) % 85 = 81, never >=82).
template <int ROWS, int OFF, int SCALE>
__device__ __forceinline__ void process4(const float* __restrict__ in,
                                         float* __restrict__ out,
                                         int f_local) {
    constexpr int ROWS85 = ROWS * 85;
    const int b   = f_local / ROWS85;          // magic-mul (const divisor)
    const int rem = f_local - b * ROWS85;      // j*85 + c within batch
    const int c0  = rem % 85;                  // channel of first element

    const bool prevNeeded = (c0 >= 1) && (c0 <= 3);
    const bool nextNeeded = (c0 >= 82);
    int nb = f_local;                          // dummy: own address
    if (prevNeeded) nb = f_local - 4;
    if (nextNeeded) nb = f_local + 4;

    const v4f x = *(const v4f*)(in + f_local);
    const v4f n = *(const v4f*)(in + nb);

    // 7-wide window, static names only (rule #20: no runtime-indexed arrays)
    const float w0 = prevNeeded ? n.x : x.x;
    const float w1 = prevNeeded ? n.y : x.y;
    const float w2 = prevNeeded ? n.z : x.z;
    const float w3 = prevNeeded ? n.w : x.w;
    const float w4 = prevNeeded ? x.x : n.x;
    const float w5 = prevNeeded ? x.y : n.y;
    const float w6 = prevNeeded ? x.z : n.z;
    const int idx = prevNeeded ? (4 - c0) : (nextNeeded ? (85 - c0) : 0);
    const bool i1 = (idx & 1) != 0;
    const bool i2 = (idx & 2) != 0;
    // funnel shift by idx (0..3): shift 2, then shift 1
    const float a0 = i2 ? w2 : w0;
    const float a1 = i2 ? w3 : w1;
    const float a2 = i2 ? w4 : w2;
    const float a3 = i2 ? w5 : w3;
    const float a4 = i2 ? w6 : w4;
    const float r0 = i1 ? a1 : a0;
    const float r1 = i1 ? a2 : a1;
    const float r2 = i1 ? a3 : a2;
    const float r3 = i1 ? a4 : a3;

    // Faithful to the torch in-place sequence (W == H == SCALE):
    const float sc = (float)SCALE;
    const float h2 = 0.5f * r2, h3 = 0.5f * r3;
    const float q0 = (r0 - h2) * sc;           // x1
    const float q1 = (r1 - h3) * sc;           // y1
    const float q2 = (q0 + h2) * sc;           // x2
    const float q3 = (q1 + h3) * sc;           // y2

    float xv[4] = {x.x, x.y, x.z, x.w};
    float y[4];
#pragma unroll
    for (int k = 0; k < 4; ++k) {
        int c = c0 + k;
        if (c >= 85) c -= 85;                  // at most one row wrap
        const float s = fast_sigmoid(xv[k]);
        const float q = (c == 0) ? q0 : ((c == 1) ? q1 : ((c == 2) ? q2 : q3));
        y[k] = (c < 4) ? q : s;                // v_cndmask chain, no branch
    }

    const int out_f = (b * NROWS_OUT + OFF) * 85 + rem;
    v4f yo; yo.x = y[0]; yo.y = y[1]; yo.z = y[2]; yo.w = y[3];
    __builtin_nontemporal_store(yo, (v4f*)(out + out_f));
}

__device__ __forceinline__ void dispatch4(const float* __restrict__ fm0,
                                          const float* __restrict__ fm1,
                                          const float* __restrict__ fm2,
                                          float* __restrict__ out, int f) {
    if (f < L0_FLOATS) {
        process4<19200, 0, 80>(fm0, out, f);
    } else if (f < L0_FLOATS + L1_FLOATS) {
        process4<4800, 19200, 40>(fm1, out, f - L0_FLOATS);
    } else {
        process4<1200, 24000, 20>(fm2, out, f - (L0_FLOATS + L1_FLOATS));
    }
}

__global__ __launch_bounds__(256) void yolo_decode_kernel(
    const float* __restrict__ fm0, const float* __restrict__ fm1,
    const float* __restrict__ fm2, float* __restrict__ out) {
    const int t = blockIdx.x * 256 + threadIdx.x;
    // Grid-stride over the first quarter; each iteration also handles the
    // mirrored float4 in quarters 2,3,4 -> 4 independent coalesced streams.
    for (int j = 0; j < NITER; ++j) {
        const int v = t + j * NTHREADS;
        if (v < Q4) {
            process4<19200, 0, 80>(fm0, out, v * 4);
            process4<19200, 0, 80>(fm0, out, (v + Q4) * 4);
            process4<19200, 0, 80>(fm0, out, (v + 2 * Q4) * 4);
            dispatch4(fm0, fm1, fm2, out, (v + 3 * Q4) * 4);
        }
    }
}

extern "C" void kernel_launch(void* const* d_in, const int* in_sizes, int n_in,
                              void* d_out, int out_size, void* d_ws, size_t ws_size,
                              hipStream_t stream) {
    const float* fm0 = (const float*)d_in[0];
    const float* fm1 = (const float*)d_in[1];
    const float* fm2 = (const float*)d_in[2];
    float* out = (float*)d_out;

    hipLaunchKernelGGL(yolo_decode_kernel, dim3(NBLOCKS), dim3(256), 0, stream,
                       fm0, fm1, fm2, out);
}

// Round 5
// 246.262 us; speedup vs baseline: 1.0014x; 1.0014x over previous
//
#include <hip/hip_runtime.h>

// Problem constants (from reference setup_inputs):
//   fm0: [16,3,80,80,85]  -> 26,112,000 floats, 19200 rows/batch, scale 80
//   fm1: [16,3,40,40,85]  ->  6,528,000 floats,  4800 rows/batch, scale 40
//   fm2: [16,3,20,20,85]  ->  1,632,000 floats,  1200 rows/batch, scale 20
//   out: [16, 25200, 85]  -> 34,272,000 floats
//
// Round-5: one-shot grid (proven best shape), 4 float4s/thread with an
// explicit {addresses -> 8 batched loads -> computes -> NT stores} phase
// structure. Round-4 counters showed VGPR_Count=16: the compiler had fully
// serialized per-thread memory ops (load-wait-compute-store convoy, 69%
// stall with no saturated pipe). Named live registers for all loads force
// ILP. Index math amortized 4x: the quarter stride 8,568,000 is a multiple
// of 85 AND of the level-0 batch stride 1,632,000, so c0 / funnel selectors
// / channel codes are shared across all four quarters; batch index advances
// by add+carry, no extra magic-div.
#define NROWS_OUT 25200
#define L0_FLOATS 26112000
#define L1_FLOATS 6528000
#define L2_FLOATS 1632000
#define TOTAL_FLOATS (L0_FLOATS + L1_FLOATS + L2_FLOATS)   // 34,272,000
#define TOTAL4   (TOTAL_FLOATS / 4)                        //  8,568,000
#define Q4       (TOTAL4 / 4)                              //  2,142,000
#define Q4F      (Q4 * 4)                                  //  8,568,000
#define R85_0    1632000                                   //  19200*85
#define STEP_REM 408000                                    //  Q4F - 5*R85_0
#define OUT85    (NROWS_OUT * 85)                          //  2,142,000
#define Q3FASTV  102000                                    //  v<this: q3 in L0

typedef float v4f __attribute__((ext_vector_type(4)));

__device__ __forceinline__ float fast_sigmoid(float x) {
    // v_exp_f32 (+1 mul) + v_rcp_f32: ~4 VALU ops, rel err ~1e-6.
    float e = __expf(-x);
    return __builtin_amdgcn_rcpf(1.0f + e);
}

__device__ __forceinline__ float pick(int c, float q0, float q1, float q2,
                                      float q3, float s) {
    const float q = (c == 0) ? q0 : ((c == 1) ? q1 : ((c == 2) ? q2 : q3));
    return (c < 4) ? q : s;                    // v_cndmask chain, no branch
}

// Per-thread selector pack, identical for all four quarters (stride Q4F is
// a multiple of 85 and of R85_0, so c0 and everything derived from it is
// quarter-invariant).
struct Sel {
    bool prevN, i1, i2;
    int cc0, cc1, cc2, cc3;                    // channel code per element
};

// Decode one loaded float4 (x) with its aligned neighbor (n). Funnel logic
// verified in rounds 3/4 (harness-passed): row floats r0..r3 live in
// [n|x] / [x|n] window; when idx==0 and c0 not 0, r* are garbage but the
// cc codes select sigmoid for all 4 elements, so they're never used.
template <int SCALE>
__device__ __forceinline__ v4f decode4(const v4f x, const v4f n, const Sel s) {
    const float w0 = s.prevN ? n.x : x.x;
    const float w1 = s.prevN ? n.y : x.y;
    const float w2 = s.prevN ? n.z : x.z;
    const float w3 = s.prevN ? n.w : x.w;
    const float w4 = s.prevN ? x.x : n.x;
    const float w5 = s.prevN ? x.y : n.y;
    const float w6 = s.prevN ? x.z : n.z;
    const float a0 = s.i2 ? w2 : w0;
    const float a1 = s.i2 ? w3 : w1;
    const float a2 = s.i2 ? w4 : w2;
    const float a3 = s.i2 ? w5 : w3;
    const float a4 = s.i2 ? w6 : w4;
    const float r0 = s.i1 ? a1 : a0;
    const float r1 = s.i1 ? a2 : a1;
    const float r2 = s.i1 ? a3 : a2;
    const float r3 = s.i1 ? a4 : a3;

    // Faithful to the torch in-place sequence (W == H == SCALE):
    const float sc = (float)SCALE;
    const float h2 = 0.5f * r2, h3 = 0.5f * r3;
    const float q0 = (r0 - h2) * sc;           // x1
    const float q1 = (r1 - h3) * sc;           // y1
    const float q2 = (q0 + h2) * sc;           // x2
    const float q3 = (q1 + h3) * sc;           // y2

    v4f y;
    y.x = pick(s.cc0, q0, q1, q2, q3, fast_sigmoid(x.x));
    y.y = pick(s.cc1, q0, q1, q2, q3, fast_sigmoid(x.y));
    y.z = pick(s.cc2, q0, q1, q2, q3, fast_sigmoid(x.z));
    y.w = pick(s.cc3, q0, q1, q2, q3, fast_sigmoid(x.w));
    return y;
}

// Self-contained slow path (levels 1/2 only, ~4.8% of threads) — exact
// round-3 process4, harness-verified.
template <int ROWS, int OFF, int SCALE>
__device__ __forceinline__ void process4(const float* __restrict__ in,
                                         float* __restrict__ out,
                                         int f_local) {
    constexpr int ROWS85 = ROWS * 85;
    const int b   = f_local / ROWS85;
    const int rem = f_local - b * ROWS85;
    const int c0  = rem % 85;

    const bool prevNeeded = (c0 >= 1) && (c0 <= 3);
    const bool nextNeeded = (c0 >= 82);
    int nb = f_local;
    if (prevNeeded) nb = f_local - 4;
    if (nextNeeded) nb = f_local + 4;

    const v4f x = *(const v4f*)(in + f_local);
    const v4f n = *(const v4f*)(in + nb);

    Sel s;
    s.prevN = prevNeeded;
    const int idx = prevNeeded ? (4 - c0) : (nextNeeded ? (85 - c0) : 0);
    s.i1 = (idx & 1) != 0;
    s.i2 = (idx & 2) != 0;
    int c1 = c0 + 1; if (c1 >= 85) c1 -= 85;
    int c2 = c0 + 2; if (c2 >= 85) c2 -= 85;
    int c3 = c0 + 3; if (c3 >= 85) c3 -= 85;
    s.cc0 = c0; s.cc1 = c1; s.cc2 = c2; s.cc3 = c3;

    const v4f y = decode4<SCALE>(x, n, s);
    const int out_f = (b * NROWS_OUT + OFF) * 85 + rem;
    __builtin_nontemporal_store(y, (v4f*)(out + out_f));
}

__device__ __forceinline__ void dispatch_slow(const float* __restrict__ fm1,
                                              const float* __restrict__ fm2,
                                              float* __restrict__ out, int f) {
    if (f < L0_FLOATS + L1_FLOATS) {
        process4<4800, 19200, 40>(fm1, out, f - L0_FLOATS);
    } else {
        process4<1200, 24000, 20>(fm2, out, f - (L0_FLOATS + L1_FLOATS));
    }
}

__global__ __launch_bounds__(256) void yolo_decode_kernel(
    const float* __restrict__ fm0, const float* __restrict__ fm1,
    const float* __restrict__ fm2, float* __restrict__ out) {
    const int v = blockIdx.x * 256 + threadIdx.x;
    if (v >= Q4) return;

    // ---- phase 1: index math (once for all four quarters) ----
    const int f0   = v * 4;
    const int b0   = f0 / R85_0;               // magic-mul (const divisor)
    const int rem0 = f0 - b0 * R85_0;
    const int c0   = rem0 % 85;                // quarter-invariant

    Sel s;
    s.prevN = (c0 >= 1) && (c0 <= 3);
    const bool nextN = (c0 >= 82);
    const int dnb = s.prevN ? -4 : (nextN ? 4 : 0);
    const int idx = s.prevN ? (4 - c0) : (nextN ? (85 - c0) : 0);
    s.i1 = (idx & 1) != 0;
    s.i2 = (idx & 2) != 0;
    int c1 = c0 + 1; if (c1 >= 85) c1 -= 85;
    int c2 = c0 + 2; if (c2 >= 85) c2 -= 85;
    int c3 = c0 + 3; if (c3 >= 85) c3 -= 85;
    s.cc0 = c0; s.cc1 = c1; s.cc2 = c2; s.cc3 = c3;

    // batch/rem advance per quarter: +Q4F = +5*R85_0 + STEP_REM
    int b1 = b0 + 5, rem1 = rem0 + STEP_REM;
    if (rem1 >= R85_0) { rem1 -= R85_0; ++b1; }
    int b2 = b1 + 5, rem2 = rem1 + STEP_REM;
    if (rem2 >= R85_0) { rem2 -= R85_0; ++b2; }

    const int f1 = f0 + Q4F;
    const int f2 = f0 + 2 * Q4F;
    const int f3 = f0 + 3 * Q4F;
    const bool q3fast = (v < Q3FASTV);         // q3 float4 still in level 0
    // In-bounds for neighbor loads: prevN => f>=4 in-buffer; nextN never
    // true on a level's last float4 (its c0 == 81). All verified round 3.

    // ---- phase 2: batched loads (up to 8 dwordx4 in flight) ----
    const v4f x0 = *(const v4f*)(fm0 + f0);
    const v4f n0 = *(const v4f*)(fm0 + f0 + dnb);
    const v4f x1 = *(const v4f*)(fm0 + f1);
    const v4f n1 = *(const v4f*)(fm0 + f1 + dnb);
    const v4f x2 = *(const v4f*)(fm0 + f2);
    const v4f n2 = *(const v4f*)(fm0 + f2 + dnb);
    v4f x3{}, n3{};
    if (q3fast) {                              // wave-uniform except 1 wave
        x3 = *(const v4f*)(fm0 + f3);
        n3 = *(const v4f*)(fm0 + f3 + dnb);
    }

    // ---- phase 3: compute + NT stores ----
    const v4f y0 = decode4<80>(x0, n0, s);
    __builtin_nontemporal_store(y0, (v4f*)(out + b0 * OUT85 + rem0));
    const v4f y1 = decode4<80>(x1, n1, s);
    __builtin_nontemporal_store(y1, (v4f*)(out + b1 * OUT85 + rem1));
    const v4f y2 = decode4<80>(x2, n2, s);
    __builtin_nontemporal_store(y2, (v4f*)(out + b2 * OUT85 + rem2));
    if (q3fast) {
        // f3 in [25,704,000, 26,112,000) => b3 == 15 always;
        // rem3 = f3 - 15*R85_0 = f0 + 1,224,000 (c0 unchanged: mult of 85).
        const v4f y3 = decode4<80>(x3, n3, s);
        __builtin_nontemporal_store(
            y3, (v4f*)(out + 15 * OUT85 + (f0 + 1224000)));
    } else {
        dispatch_slow(fm1, fm2, out, f3);      // levels 1/2, ~4.8% of threads
    }
}

extern "C" void kernel_launch(void* const* d_in, const int* in_sizes, int n_in,
                              void* d_out, int out_size, void* d_ws, size_t ws_size,
                              hipStream_t stream) {
    const float* fm0 = (const float*)d_in[0];
    const float* fm1 = (const float*)d_in[1];
    const float* fm2 = (const float*)d_in[2];
    float* out = (float*)d_out;

    const int blocks = (Q4 + 255) / 256;       // 8,368
    hipLaunchKernelGGL(yolo_decode_kernel, dim3(blocks), dim3(256), 0, stream,
                       fm0, fm1, fm2, out);
}

// Round 8
// 232.435 us; speedup vs baseline: 1.0609x; 1.0595x over previous
//
#include <hip/hip_runtime.h>

// Problem constants (from reference setup_inputs):
//   fm0: [16,3,80,80,85]  -> 26,112,000 floats, 19200 rows/batch, scale 80
//   fm1: [16,3,40,40,85]  ->  6,528,000 floats,  4800 rows/batch, scale 40
//   fm2: [16,3,20,20,85]  ->  1,632,000 floats,  1200 rows/batch, scale 20
//   out: [16, 25200, 85]  -> 34,272,000 floats
//
// Round-8 = round-6 experiment with the single novel syntax element removed:
// plain __launch_bounds__(256) (rounds 6/7 had "(256, 8)" and were the only
// two rounds ever to die with "container failed twice"; every kernel with
// plain (256) ran). Tests the same hypothesis as round 6:
//
// Endpoint of the only lever that has moved this kernel. Measured gradient:
// 4 f4/thread = 84 us, 2 f4/thread = 72-75 us, with instruction count /
// store type / ILP / grid-stride all proven null. Mechanism: freshly
// dispatched blocks issue their loads immediately with no intra-thread
// vmcnt dependency -> block churn IS the memory pipeline (the compiler
// refuses to build one inside a thread: r5 kept VGPR=24). So: 1 float4 per
// thread, 33,469 one-shot blocks, 3 VMEM per thread, NT stores.
#define NROWS_OUT 25200
#define L0_FLOATS 26112000
#define L1_FLOATS 6528000
#define L2_FLOATS 1632000
#define TOTAL_FLOATS (L0_FLOATS + L1_FLOATS + L2_FLOATS)   // 34,272,000
#define TOTAL4   (TOTAL_FLOATS / 4)                        //  8,568,000

typedef float v4f __attribute__((ext_vector_type(4)));

__device__ __forceinline__ float fast_sigmoid(float x) {
    // v_exp_f32 (+1 mul) + v_rcp_f32: ~4 VALU ops, rel err ~1e-6.
    float e = __expf(-x);
    return __builtin_amdgcn_rcpf(1.0f + e);
}

// One aligned float4 of a level's flat buffer. ROWS/OFF/SCALE compile-time.
// Harness-verified in rounds 3/4/5 (absmax 0.0039, passed).
//
// Alignment: f_local % 4 == 0; output shift per (b,level) is a multiple of
// 4 floats for all levels, so load and store are 16B-aligned.
//
// Row-float reconstruction (1 vec load instead of 4 scalar loads):
//   needed row floats beyond our own x are all inside ONE aligned neighbor
//   float4: prev (f-4) for c0 in 1..3, next (f+4) for c0 in 82..84, none
//   otherwise (neighbor load degenerates to own address -> L1 hit).
//   In-bounds: c0 in 1..3 => f>=4; c0>=82 => next row exists in full (last
//   float4 of a level has c0 = (ROWS85-4) % 85 = 81, never >=82).
template <int ROWS, int OFF, int SCALE>
__device__ __forceinline__ void process4(const float* __restrict__ in,
                                         float* __restrict__ out,
                                         int f_local) {
    constexpr int ROWS85 = ROWS * 85;
    const int b   = f_local / ROWS85;          // magic-mul (const divisor)
    const int rem = f_local - b * ROWS85;      // j*85 + c within batch
    const int c0  = rem % 85;                  // channel of first element

    const bool prevNeeded = (c0 >= 1) && (c0 <= 3);
    const bool nextNeeded = (c0 >= 82);
    int nb = f_local;                          // dummy: own address
    if (prevNeeded) nb = f_local - 4;
    if (nextNeeded) nb = f_local + 4;

    const v4f x = *(const v4f*)(in + f_local);
    const v4f n = *(const v4f*)(in + nb);

    // 7-wide window, static names only (rule #20: no runtime-indexed arrays)
    const float w0 = prevNeeded ? n.x : x.x;
    const float w1 = prevNeeded ? n.y : x.y;
    const float w2 = prevNeeded ? n.z : x.z;
    const float w3 = prevNeeded ? n.w : x.w;
    const float w4 = prevNeeded ? x.x : n.x;
    const float w5 = prevNeeded ? x.y : n.y;
    const float w6 = prevNeeded ? x.z : n.z;
    const int idx = prevNeeded ? (4 - c0) : (nextNeeded ? (85 - c0) : 0);
    const bool i1 = (idx & 1) != 0;
    const bool i2 = (idx & 2) != 0;
    // funnel shift by idx (0..3): shift 2, then shift 1
    const float a0 = i2 ? w2 : w0;
    const float a1 = i2 ? w3 : w1;
    const float a2 = i2 ? w4 : w2;
    const float a3 = i2 ? w5 : w3;
    const float a4 = i2 ? w6 : w4;
    const float r0 = i1 ? a1 : a0;
    const float r1 = i1 ? a2 : a1;
    const float r2 = i1 ? a3 : a2;
    const float r3 = i1 ? a4 : a3;

    // Faithful to the torch in-place sequence (W == H == SCALE):
    const float sc = (float)SCALE;
    const float h2 = 0.5f * r2, h3 = 0.5f * r3;
    const float q0 = (r0 - h2) * sc;           // x1
    const float q1 = (r1 - h3) * sc;           // y1
    const float q2 = (q0 + h2) * sc;           // x2
    const float q3 = (q1 + h3) * sc;           // y2

    float xv[4] = {x.x, x.y, x.z, x.w};
    float y[4];
#pragma unroll
    for (int k = 0; k < 4; ++k) {
        int c = c0 + k;
        if (c >= 85) c -= 85;                  // at most one row wrap
        const float s = fast_sigmoid(xv[k]);
        const float q = (c == 0) ? q0 : ((c == 1) ? q1 : ((c == 2) ? q2 : q3));
        y[k] = (c < 4) ? q : s;                // v_cndmask chain, no branch
    }

    const int out_f = (b * NROWS_OUT + OFF) * 85 + rem;
    v4f yo; yo.x = y[0]; yo.y = y[1]; yo.z = y[2]; yo.w = y[3];
    __builtin_nontemporal_store(yo, (v4f*)(out + out_f));
}

__device__ __forceinline__ void dispatch4(const float* __restrict__ fm0,
                                          const float* __restrict__ fm1,
                                          const float* __restrict__ fm2,
                                          float* __restrict__ out, int f) {
    if (f < L0_FLOATS) {                       // 76.2% of threads
        process4<19200, 0, 80>(fm0, out, f);
    } else if (f < L0_FLOATS + L1_FLOATS) {
        process4<4800, 19200, 40>(fm1, out, f - L0_FLOATS);
    } else {
        process4<1200, 24000, 20>(fm2, out, f - (L0_FLOATS + L1_FLOATS));
    }
}

__global__ __launch_bounds__(256) void yolo_decode_kernel(
    const float* __restrict__ fm0, const float* __restrict__ fm1,
    const float* __restrict__ fm2, float* __restrict__ out) {
    // One float4 per thread: maximal block-level load parallelism, minimal
    // per-thread serial convoy. Consecutive lanes -> consecutive float4s.
    const int v = blockIdx.x * 256 + threadIdx.x;
    if (v >= TOTAL4) return;
    dispatch4(fm0, fm1, fm2, out, v * 4);
}

extern "C" void kernel_launch(void* const* d_in, const int* in_sizes, int n_in,
                              void* d_out, int out_size, void* d_ws, size_t ws_size,
                              hipStream_t stream) {
    const float* fm0 = (const float*)d_in[0];
    const float* fm1 = (const float*)d_in[1];
    const float* fm2 = (const float*)d_in[2];
    float* out = (float*)d_out;

    const int blocks = (TOTAL4 + 255) / 256;   // 33,469
    hipLaunchKernelGGL(yolo_decode_kernel, dim3(blocks), dim3(256), 0, stream,
                       fm0, fm1, fm2, out);
}